// Round 1
// baseline (242.088 us; speedup 1.0000x reference)
//
#include <hip/hip_runtime.h>
#include <hip/hip_bf16.h>

#define NB 16
#define CDIM 512
#define HWDIM 3136

typedef __attribute__((ext_vector_type(8))) short bf16x8;
typedef __attribute__((ext_vector_type(4))) float f32x4;

#define GLOAD_LDS(g, l) \
  __builtin_amdgcn_global_load_lds((const __attribute__((address_space(1))) void*)(g), \
                                   (__attribute__((address_space(3))) void*)(l), 16, 0, 0)

__device__ inline unsigned short f2bf(float f) {
  unsigned u = __float_as_uint(f);
  u += 0x7fffu + ((u >> 16) & 1u);
  return (unsigned short)(u >> 16);
}

__device__ inline float blk_max(float v, float* red) {
  for (int o = 32; o > 0; o >>= 1) v = fmaxf(v, __shfl_xor(v, o));
  if ((threadIdx.x & 63) == 0) red[threadIdx.x >> 6] = v;
  __syncthreads();
  float r = fmaxf(fmaxf(red[0], red[1]), fmaxf(red[2], red[3]));
  __syncthreads();
  return r;
}

__device__ inline float blk_sum(float v, float* red) {
  for (int o = 32; o > 0; o >>= 1) v += __shfl_xor(v, o);
  if ((threadIdx.x & 63) == 0) red[threadIdx.x >> 6] = v;
  __syncthreads();
  float r = red[0] + red[1] + red[2] + red[3];
  __syncthreads();
  return r;
}

// K1: per (n,c) row: write f as bf16, and softmax(2f) as bf16.
__global__ __launch_bounds__(256) void k_softmax_hw(const float* __restrict__ x,
                                                    unsigned short* __restrict__ fbf,
                                                    unsigned short* __restrict__ fnorm) {
  __shared__ float red[4];
  const int row = blockIdx.x;
  const float4* xr = (const float4*)(x + (size_t)row * HWDIM);
  float4 v[4];
  int n = 0;
  float lmax = -3.4e38f;
  for (int i = threadIdx.x; i < HWDIM / 4; i += 256) {
    float4 t = xr[i];
    v[n++] = t;
    lmax = fmaxf(fmaxf(fmaxf(t.x, t.y), fmaxf(t.z, t.w)), lmax);
  }
  const float M = 2.0f * blk_max(lmax, red);
  float lsum = 0.f;
  n = 0;
  for (int i = threadIdx.x; i < HWDIM / 4; i += 256) {
    float4 t = v[n];
    ushort4 ob;
    ob.x = f2bf(t.x); ob.y = f2bf(t.y); ob.z = f2bf(t.z); ob.w = f2bf(t.w);
    *(ushort4*)(fbf + (size_t)row * HWDIM + i * 4) = ob;
    float4 e;
    e.x = __expf(2.f * t.x - M); e.y = __expf(2.f * t.y - M);
    e.z = __expf(2.f * t.z - M); e.w = __expf(2.f * t.w - M);
    lsum += e.x + e.y + e.z + e.w;
    v[n] = e; n++;
  }
  const float inv = 1.0f / blk_sum(lsum, red);
  n = 0;
  for (int i = threadIdx.x; i < HWDIM / 4; i += 256) {
    float4 e = v[n++];
    ushort4 ob;
    ob.x = f2bf(e.x * inv); ob.y = f2bf(e.y * inv);
    ob.z = f2bf(e.z * inv); ob.w = f2bf(e.w * inv);
    *(ushort4*)(fnorm + (size_t)row * HWDIM + i * 4) = ob;
  }
}

// K2: bf16 transpose [C][HW] -> [HW][C], 64x64 tiles.
__global__ __launch_bounds__(256) void k_transpose(const unsigned short* __restrict__ fbf,
                                                   unsigned short* __restrict__ fT) {
  __shared__ unsigned short tile[64][66];
  const int b = blockIdx.z;
  const int hw0 = blockIdx.x * 64;
  const int c0 = blockIdx.y * 64;
  const unsigned short* src = fbf + (size_t)b * CDIM * HWDIM;
  unsigned short* dst = fT + (size_t)b * HWDIM * CDIM;
  const int tr = threadIdx.x >> 4;
  const int tc4 = (threadIdx.x & 15) * 4;
  for (int r = tr; r < 64; r += 16) {
    ushort4 t = *(const ushort4*)(src + (size_t)(c0 + r) * HWDIM + hw0 + tc4);
    tile[r][tc4] = t.x; tile[r][tc4 + 1] = t.y; tile[r][tc4 + 2] = t.z; tile[r][tc4 + 3] = t.w;
  }
  __syncthreads();
  for (int r = tr; r < 64; r += 16) {
    ushort4 t;
    t.x = tile[tc4][r]; t.y = tile[tc4 + 1][r]; t.z = tile[tc4 + 2][r]; t.w = tile[tc4 + 3][r];
    *(ushort4*)(dst + (size_t)(hw0 + r) * CDIM + c0 + tc4) = t;
  }
}

// K4: row softmax over 512 channels -> bf16.
__global__ __launch_bounds__(256) void k_softmax_c(const float* __restrict__ bil,
                                                   unsigned short* __restrict__ bsm) {
  __shared__ float red[4];
  const int row = blockIdx.x;
  const float* r = bil + (size_t)row * CDIM;
  const float a = r[threadIdx.x];
  const float b = r[threadIdx.x + 256];
  const float M = blk_max(fmaxf(a, b), red);
  const float ea = __expf(a - M), eb = __expf(b - M);
  const float inv = 1.0f / blk_sum(ea + eb, red);
  bsm[(size_t)row * CDIM + threadIdx.x] = f2bf(ea * inv);
  bsm[(size_t)row * CDIM + threadIdx.x + 256] = f2bf(eb * inv);
}

// Batched C = A * B^T.  A:[M][K] bf16, B:[N][K] bf16, C:[M][N] f32.
// 64x64 block tile, BK=32, 4 waves each computing a 32x32 quadrant.
// Requires M%64==0, N%64==0, K%32==0.
__global__ __launch_bounds__(256) void k_gemm_bt64(const unsigned short* __restrict__ Ag,
                                                   const unsigned short* __restrict__ Bg,
                                                   float* __restrict__ Cg,
                                                   int M, int N, int K) {
  __shared__ __align__(16) unsigned short As[64 * 32];
  __shared__ __align__(16) unsigned short Bs[64 * 32];
  const int b = blockIdx.z;
  const unsigned short* A = Ag + (size_t)b * M * K;
  const unsigned short* B = Bg + (size_t)b * N * K;
  float* C = Cg + (size_t)b * M * N;
  const int brow = blockIdx.y * 64;
  const int bcol = blockIdx.x * 64;
  const int tid = threadIdx.x;
  const int lane = tid & 63;
  const int wave = tid >> 6;
  const int wr = wave >> 1;
  const int wc = wave & 1;

  f32x4 acc[2][2] = {};

  // staging: wave w stages 16 rows (1 KiB) of each tile; lane l -> row w*16 + l/4, k (l%4)*8
  const int lrow = (wave << 4) + (lane >> 2);
  const int kc = (lane & 3) << 3;
  const size_t aoff = (size_t)(brow + lrow) * K + kc;
  const size_t boff = (size_t)(bcol + lrow) * K + kc;
  unsigned short* asb = As + (wave << 9);
  unsigned short* bsb = Bs + (wave << 9);

  for (int k0 = 0; k0 < K; k0 += 32) {
    GLOAD_LDS(A + aoff + k0, asb);
    GLOAD_LDS(B + boff + k0, bsb);
    __syncthreads();
    bf16x8 af[2], bfr[2];
#pragma unroll
    for (int i = 0; i < 2; ++i) {
      af[i]  = *(const bf16x8*)(As + ((wr << 5) + (i << 4) + (lane & 15)) * 32 + ((lane >> 4) << 3));
      bfr[i] = *(const bf16x8*)(Bs + ((wc << 5) + (i << 4) + (lane & 15)) * 32 + ((lane >> 4) << 3));
    }
#pragma unroll
    for (int i = 0; i < 2; ++i)
#pragma unroll
      for (int j = 0; j < 2; ++j)
        acc[i][j] = __builtin_amdgcn_mfma_f32_16x16x32_bf16(af[i], bfr[j], acc[i][j], 0, 0, 0);
    __syncthreads();
  }

  // D layout: col = lane&15, row = (lane>>4)*4 + reg
  const int crow = brow + (wr << 5) + ((lane >> 4) << 2);
  const int ccol = bcol + (wc << 5) + (lane & 15);
#pragma unroll
  for (int i = 0; i < 2; ++i)
#pragma unroll
    for (int j = 0; j < 2; ++j) {
      float* cp = C + (size_t)(crow + (i << 4)) * N + ccol + (j << 4);
#pragma unroll
      for (int r = 0; r < 4; ++r) cp[(size_t)r * N] = acc[i][j][r];
    }
}

extern "C" void kernel_launch(void* const* d_in, const int* in_sizes, int n_in,
                              void* d_out, int out_size, void* d_ws, size_t ws_size,
                              hipStream_t stream) {
  const float* x = (const float*)d_in[0];
  float* out = (float*)d_out;
  char* ws = (char*)d_ws;
  const size_t fbytes = (size_t)NB * CDIM * HWDIM * 2;  // 51,380,224 B

  unsigned short* fbf   = (unsigned short*)ws;            // f in bf16 [n][c][hw]
  unsigned short* fnorm = (unsigned short*)(ws + fbytes); // softmax(2f) bf16 [n][c][hw]
  unsigned short* fT    = fnorm;                          // reuse after GEMM-1: f^T bf16 [n][hw][c]
  unsigned short* bsm   = (unsigned short*)ws;            // reuse fbf region after transpose
  float* bil = out;                                       // bilinear scratch in d_out (16.8 MB)

  // 1. softmax over hw (+ bf16 casts)
  k_softmax_hw<<<NB * CDIM, 256, 0, stream>>>(x, fbf, fnorm);
  // 2. bilinear = fnorm @ f^T   (M=512, N=512, K=3136)
  k_gemm_bt64<<<dim3(CDIM / 64, CDIM / 64, NB), 256, 0, stream>>>(fnorm, fbf, bil, CDIM, CDIM, HWDIM);
  // 3. f^T for the second GEMM (overwrites fnorm region)
  k_transpose<<<dim3(HWDIM / 64, CDIM / 64, NB), 256, 0, stream>>>(fbf, fT);
  // 4. softmax over channels -> bf16 (overwrites fbf region)
  k_softmax_c<<<NB * CDIM, 256, 0, stream>>>(bil, bsm);
  // 5. out = bsm @ f   (M=512, N=3136, K=512)  via A[M][K] * B[N][K]^T with B = f^T
  k_gemm_bt64<<<dim3(HWDIM / 64, CDIM / 64, NB), 256, 0, stream>>>(bsm, fT, out, CDIM, HWDIM, CDIM);
}

// Round 2
// 219.642 us; speedup vs baseline: 1.1022x; 1.1022x over previous
//
#include <hip/hip_runtime.h>
#include <hip/hip_bf16.h>

#define NB 16
#define CDIM 512
#define HWDIM 3136

typedef __attribute__((ext_vector_type(8))) short bf16x8;
typedef __attribute__((ext_vector_type(4))) float f32x4;

#define GLOAD_LDS(g, l) \
  __builtin_amdgcn_global_load_lds((const __attribute__((address_space(1))) void*)(g), \
                                   (__attribute__((address_space(3))) void*)(l), 16, 0, 0)

__device__ inline unsigned short f2bf(float f) {
  unsigned u = __float_as_uint(f);
  u += 0x7fffu + ((u >> 16) & 1u);
  return (unsigned short)(u >> 16);
}

__device__ inline float blk_max(float v, float* red) {
  for (int o = 32; o > 0; o >>= 1) v = fmaxf(v, __shfl_xor(v, o));
  if ((threadIdx.x & 63) == 0) red[threadIdx.x >> 6] = v;
  __syncthreads();
  float r = fmaxf(fmaxf(red[0], red[1]), fmaxf(red[2], red[3]));
  __syncthreads();
  return r;
}

__device__ inline float blk_sum(float v, float* red) {
  for (int o = 32; o > 0; o >>= 1) v += __shfl_xor(v, o);
  if ((threadIdx.x & 63) == 0) red[threadIdx.x >> 6] = v;
  __syncthreads();
  float r = red[0] + red[1] + red[2] + red[3];
  __syncthreads();
  return r;
}

// K1: per (n,c) row: write f as bf16, and softmax(2f) as bf16.
__global__ __launch_bounds__(256) void k_softmax_hw(const float* __restrict__ x,
                                                    unsigned short* __restrict__ fbf,
                                                    unsigned short* __restrict__ fnorm) {
  __shared__ float red[4];
  const int row = blockIdx.x;
  const float4* xr = (const float4*)(x + (size_t)row * HWDIM);
  float4 v[4];
  int n = 0;
  float lmax = -3.4e38f;
  for (int i = threadIdx.x; i < HWDIM / 4; i += 256) {
    float4 t = xr[i];
    v[n++] = t;
    lmax = fmaxf(fmaxf(fmaxf(t.x, t.y), fmaxf(t.z, t.w)), lmax);
  }
  const float M = 2.0f * blk_max(lmax, red);
  float lsum = 0.f;
  n = 0;
  for (int i = threadIdx.x; i < HWDIM / 4; i += 256) {
    float4 t = v[n];
    ushort4 ob;
    ob.x = f2bf(t.x); ob.y = f2bf(t.y); ob.z = f2bf(t.z); ob.w = f2bf(t.w);
    *(ushort4*)(fbf + (size_t)row * HWDIM + i * 4) = ob;
    float4 e;
    e.x = __expf(2.f * t.x - M); e.y = __expf(2.f * t.y - M);
    e.z = __expf(2.f * t.z - M); e.w = __expf(2.f * t.w - M);
    lsum += e.x + e.y + e.z + e.w;
    v[n] = e; n++;
  }
  const float inv = 1.0f / blk_sum(lsum, red);
  n = 0;
  for (int i = threadIdx.x; i < HWDIM / 4; i += 256) {
    float4 e = v[n++];
    ushort4 ob;
    ob.x = f2bf(e.x * inv); ob.y = f2bf(e.y * inv);
    ob.z = f2bf(e.z * inv); ob.w = f2bf(e.w * inv);
    *(ushort4*)(fnorm + (size_t)row * HWDIM + i * 4) = ob;
  }
}

// K2: bf16 transpose [C][HW] -> [HW][C], 64x64 tiles.
__global__ __launch_bounds__(256) void k_transpose(const unsigned short* __restrict__ fbf,
                                                   unsigned short* __restrict__ fT) {
  __shared__ unsigned short tile[64][66];
  const int b = blockIdx.z;
  const int hw0 = blockIdx.x * 64;
  const int c0 = blockIdx.y * 64;
  const unsigned short* src = fbf + (size_t)b * CDIM * HWDIM;
  unsigned short* dst = fT + (size_t)b * HWDIM * CDIM;
  const int tr = threadIdx.x >> 4;
  const int tc4 = (threadIdx.x & 15) * 4;
  for (int r = tr; r < 64; r += 16) {
    ushort4 t = *(const ushort4*)(src + (size_t)(c0 + r) * HWDIM + hw0 + tc4);
    tile[r][tc4] = t.x; tile[r][tc4 + 1] = t.y; tile[r][tc4 + 2] = t.z; tile[r][tc4 + 3] = t.w;
  }
  __syncthreads();
  for (int r = tr; r < 64; r += 16) {
    ushort4 t;
    t.x = tile[tc4][r]; t.y = tile[tc4 + 1][r]; t.z = tile[tc4 + 2][r]; t.w = tile[tc4 + 3][r];
    *(ushort4*)(dst + (size_t)(hw0 + r) * CDIM + c0 + tc4) = t;
  }
}

// K4: row softmax over 512 channels -> bf16.
__global__ __launch_bounds__(256) void k_softmax_c(const float* __restrict__ bil,
                                                   unsigned short* __restrict__ bsm) {
  __shared__ float red[4];
  const int row = blockIdx.x;
  const float* r = bil + (size_t)row * CDIM;
  const float a = r[threadIdx.x];
  const float b = r[threadIdx.x + 256];
  const float M = blk_max(fmaxf(a, b), red);
  const float ea = __expf(a - M), eb = __expf(b - M);
  const float inv = 1.0f / blk_sum(ea + eb, red);
  bsm[(size_t)row * CDIM + threadIdx.x] = f2bf(ea * inv);
  bsm[(size_t)row * CDIM + threadIdx.x + 256] = f2bf(eb * inv);
}

// Batched C = A * B^T.  A:[M][K] bf16, B:[N][K] bf16, C:[M][N] f32.
// BM=128, BN=64, BK=32. 4 waves in 2x2; each wave computes 64x32 (4x2 frags).
// m97-style 2-barrier loop with global_load_lds width-16 staging.
// Requires M%128==0, N%64==0, K%32==0.
__global__ __launch_bounds__(256) void k_gemm_bt(const unsigned short* __restrict__ Ag,
                                                 const unsigned short* __restrict__ Bg,
                                                 float* __restrict__ Cg,
                                                 int M, int N, int K) {
  __shared__ __align__(16) unsigned short As[128 * 32];  // 8 KiB
  __shared__ __align__(16) unsigned short Bs[64 * 32];   // 4 KiB
  const int b = blockIdx.z;
  const unsigned short* A = Ag + (size_t)b * M * K;
  const unsigned short* B = Bg + (size_t)b * N * K;
  float* C = Cg + (size_t)b * M * N;
  const int brow = blockIdx.y * 128;
  const int bcol = blockIdx.x * 64;
  const int tid = threadIdx.x;
  const int lane = tid & 63;
  const int wave = tid >> 6;
  const int wr = wave >> 1;  // 0..1 over M (64 rows each)
  const int wc = wave & 1;   // 0..1 over N (32 cols each)

  f32x4 acc[4][2] = {};

  // Staging addresses. gload_lds writes wave_base + lane*16; our linear row-major
  // LDS layout matches lane -> (row = lane/4, col8 = lane%4) within each 1 KiB chunk.
  const int srow = (wave << 4) + (lane >> 2);  // 0..63
  const int skc = (lane & 3) << 3;             // 0,8,16,24
  const unsigned short* pa0 = A + (size_t)(brow + srow) * K + skc;
  const unsigned short* pa1 = pa0 + (size_t)64 * K;
  const unsigned short* pb  = B + (size_t)(bcol + srow) * K + skc;
  unsigned short* asd0 = As + (wave << 9);          // rows 0..63
  unsigned short* asd1 = As + 2048 + (wave << 9);   // rows 64..127
  unsigned short* bsd  = Bs + (wave << 9);

  const int kh = (lane >> 4) << 3;      // k-half offset within BK=32
  const int fr = lane & 15;             // fragment row within 16

  for (int k0 = 0; k0 < K; k0 += 32) {
    GLOAD_LDS(pa0 + k0, asd0);
    GLOAD_LDS(pa1 + k0, asd1);
    GLOAD_LDS(pb + k0, bsd);
    __syncthreads();
    bf16x8 af[4], bfv[2];
#pragma unroll
    for (int i = 0; i < 4; ++i)
      af[i] = *(const bf16x8*)(As + ((wr << 6) + (i << 4) + fr) * 32 + kh);
#pragma unroll
    for (int j = 0; j < 2; ++j)
      bfv[j] = *(const bf16x8*)(Bs + ((wc << 5) + (j << 4) + fr) * 32 + kh);
#pragma unroll
    for (int i = 0; i < 4; ++i)
#pragma unroll
      for (int j = 0; j < 2; ++j)
        acc[i][j] = __builtin_amdgcn_mfma_f32_16x16x32_bf16(af[i], bfv[j], acc[i][j], 0, 0, 0);
    __syncthreads();
  }

  // D layout: col = lane&15, row = (lane>>4)*4 + reg
  const int crow = brow + (wr << 6) + ((lane >> 4) << 2);
  const int ccol = bcol + (wc << 5) + fr;
#pragma unroll
  for (int i = 0; i < 4; ++i)
#pragma unroll
    for (int j = 0; j < 2; ++j) {
      float* cp = C + (size_t)(crow + (i << 4)) * N + ccol + (j << 4);
#pragma unroll
      for (int r = 0; r < 4; ++r) cp[(size_t)r * N] = acc[i][j][r];
    }
}

extern "C" void kernel_launch(void* const* d_in, const int* in_sizes, int n_in,
                              void* d_out, int out_size, void* d_ws, size_t ws_size,
                              hipStream_t stream) {
  const float* x = (const float*)d_in[0];
  float* out = (float*)d_out;
  char* ws = (char*)d_ws;
  const size_t fbytes = (size_t)NB * CDIM * HWDIM * 2;  // 51,380,224 B

  unsigned short* fbf   = (unsigned short*)ws;            // f in bf16 [n][c][hw]
  unsigned short* fnorm = (unsigned short*)(ws + fbytes); // softmax(2f) bf16 [n][c][hw]
  unsigned short* fT    = fnorm;                          // reuse after GEMM-1: f^T bf16 [n][hw][c]
  unsigned short* bsm   = (unsigned short*)ws;            // reuse fbf region after transpose
  float* bil = out;                                       // bilinear scratch in d_out (16.8 MB)

  // 1. softmax over hw (+ bf16 casts)
  k_softmax_hw<<<NB * CDIM, 256, 0, stream>>>(x, fbf, fnorm);
  // 2. bilinear = fnorm @ f^T   (M=512, N=512, K=3136)
  k_gemm_bt<<<dim3(CDIM / 64, CDIM / 128, NB), 256, 0, stream>>>(fnorm, fbf, bil, CDIM, CDIM, HWDIM);
  // 3. f^T for the second GEMM (overwrites fnorm region)
  k_transpose<<<dim3(HWDIM / 64, CDIM / 64, NB), 256, 0, stream>>>(fbf, fT);
  // 4. softmax over channels -> bf16 (overwrites fbf region)
  k_softmax_c<<<NB * CDIM, 256, 0, stream>>>(bil, bsm);
  // 5. out = bsm @ f   (M=512, N=3136, K=512)  via A[M][K] * B[N][K]^T with B = f^T
  k_gemm_bt<<<dim3(HWDIM / 64, CDIM / 128, NB), 256, 0, stream>>>(bsm, fT, out, CDIM, HWDIM, CDIM);
}